// Round 1
// 230.105 us; speedup vs baseline: 1.2361x; 1.2361x over previous
//
#include <hip/hip_runtime.h>

#define Bb 8
#define Nn 64
#define Hh 152
#define Ww 272
#define HW (Hh * Ww)
#define EMB 128
#define NC 500
#define EPSV 1e-4f

// ---------------------------------------------------------------------------
// Grid layout:
//   HM blocks:   8 batches x 32 row-tiles (5 rows x 272 cols each) = 256
//                (tile covers rows [tile*5, tile*5+5); rows>=152 -> idle)
//   SAMP blocks: one block per sample = 8*64 = 512   (was 8 serial/block)
// partials: float[TOTAL_BLOCKS][8] in d_ws. slots: 0=bs 1=off 2=pos 3=neg
// 4=npos 5=ce. Every block overwrites its full row -> no zeroing needed.
// ---------------------------------------------------------------------------
#define ROWS_PER_TILE 5
#define TILES 32
#define HM_BLOCKS (Bb * TILES)            // 256
#define SAMP_BLOCKS (Bb * Nn)             // 512
#define TOTAL_BLOCKS (HM_BLOCKS + SAMP_BLOCKS)

__global__ void main_kernel(const float* __restrict__ hm,
                            const float* __restrict__ bs,
                            const float* __restrict__ off,
                            const float* __restrict__ reid,
                            const float* __restrict__ gt,
                            const float* __restrict__ Wc,
                            const float* __restrict__ bc,
                            float* __restrict__ partials) {
    __shared__ int   s_r[Nn];
    __shared__ int   s_c[Nn];
    __shared__ int   s_list[Nn];   // row-bucketed center indices (ascending n)
    __shared__ int   s_cnt;
    __shared__ float s_red[12];
    __shared__ float s_feat[EMB];
    __shared__ float s_log[NC];
    __shared__ float s_max4[4];
    __shared__ float s_sum4[4];

    const int gb = blockIdx.x;
    const int t = threadIdx.x;
    const int wave = t >> 6;
    const int lane = t & 63;

    float out0 = 0.0f, out1 = 0.0f, out2 = 0.0f,
          out3 = 0.0f, out4 = 0.0f, out5 = 0.0f;

    if (gb < HM_BLOCKS) {
        // ----------------- heatmap focal loss (row-tiled) -----------------
        const int b = gb >> 5;
        const int tile = gb & 31;
        const int r0 = tile * ROWS_PER_TILE;

        // Wave 0: compute all 64 centers AND build the bucket of centers
        // whose 5x5 footprint intersects rows [r0, r0+ROWS_PER_TILE).
        // Ballot+prefix keeps ascending-n order -> gh sum order identical
        // to the previous (verified absmax==0) kernel.
        if (t < Nn) {
            const float* g5 = gt + ((size_t)b * Nn + t) * 5;
            float rf = g5[2] * (float)Hh;
            float cf = g5[1] * (float)Ww;
            int rr = (int)floorf(rf); rr = min(max(rr, 0), Hh - 1);
            int cc = (int)floorf(cf); cc = min(max(cc, 0), Ww - 1);
            s_r[t] = rr;
            s_c[t] = cc;
            const bool inr = (rr >= r0 - 2) && (rr <= r0 + ROWS_PER_TILE + 1);
            const unsigned long long m = __ballot(inr);
            if (inr) {
                const int idx = __popcll(m & ((1ull << t) - 1ull));
                s_list[idx] = t;
            }
            if (t == 0) s_cnt = (int)__popcll(m);
        }
        __syncthreads();

        // taps: exp(-((i-2)/3)^2/2); tap[2]==1.0 exactly. pos test gh==1.0
        // robust: min 2-tap product 0.641 -> multi-touch >= 1.28.
        float g[5];
#pragma unroll
        for (int i = 0; i < 5; ++i) {
            float tv = (float)(i - 2) / 3.0f;
            g[i] = expf(-0.5f * tv * tv);
        }

        float pos_l = 0.0f, neg_l = 0.0f, np = 0.0f;
        const int rows = min(ROWS_PER_TILE, Hh - r0);   // <=0 for tile 31
        if (rows > 0) {
            const float* hmb = hm + (size_t)b * HW + (size_t)r0 * Ww;
            const int npix = rows * Ww;                 // <= 1360
            const int cnt = s_cnt;                      // block-uniform

            for (int p = t; p < npix; p += 256) {
                int y = p / Ww;
                int x = p - y * Ww;
                int yy = r0 + y;
                float h = hmb[p];
                float pred = 1.0f / (1.0f + expf(-h));
                pred = fminf(fmaxf(pred, EPSV), 1.0f - EPSV);

                float gh = 0.0f;
                for (int j = 0; j < cnt; ++j) {
                    const int n = s_list[j];
                    int dy = yy - s_r[n];
                    int dx = x - s_c[n];
                    if (dy >= -2 && dy <= 2 && dx >= -2 && dx <= 2)
                        gh += g[dy + 2] * g[dx + 2];
                }

                if (gh == 1.0f) {
                    float om = 1.0f - pred;
                    pos_l += om * om * logf(pred);
                    np += 1.0f;
                } else if (gh < 1.0f) {
                    float om = 1.0f - gh;
                    float w = om * om;
                    w = w * w;
                    neg_l += w * pred * pred * logf(1.0f - pred);
                }
            }
        }

        // wave reduce then cross-wave via LDS
#pragma unroll
        for (int o = 32; o > 0; o >>= 1) {
            pos_l += __shfl_down(pos_l, o);
            neg_l += __shfl_down(neg_l, o);
            np    += __shfl_down(np, o);
        }
        if (lane == 0) {
            s_red[wave]      = pos_l;
            s_red[wave + 4]  = neg_l;
            s_red[wave + 8]  = np;
        }
        __syncthreads();
        if (t == 0) {
            out2 = s_red[0] + s_red[1] + s_red[2] + s_red[3];
            out3 = s_red[4] + s_red[5] + s_red[6] + s_red[7];
            out4 = s_red[8] + s_red[9] + s_red[10] + s_red[11];
        }
    } else {
        // ----------------- one sample per block: ReID CE + L1 -----------------
        const int s = gb - HM_BLOCKS;      // 0..511
        const int b = s >> 6;
        const int n = s & 63;

        const float* g5 = gt + ((size_t)b * Nn + n) * 5;
        const float tf = g5[0];
        const float xc = g5[1], yc = g5[2];
        const float bw = g5[3], bh = g5[4];

        const float rf = yc * (float)Hh;
        const float cf = xc * (float)Ww;
        const float fr = floorf(rf);
        const float fc = floorf(cf);
        const int rr = min(max((int)fr, 0), Hh - 1);
        const int cc = min(max((int)fc, 0), Ww - 1);
        const size_t pix = (size_t)rr * Ww + cc;

        if (t < EMB)
            s_feat[t] = reid[(size_t)b * EMB * HW + (size_t)t * HW + pix];
        __syncthreads();

        // thread-per-class, 2 classes/thread, float4 row reads
        float lmax = -INFINITY;
        const float4* f4 = (const float4*)s_feat;
#pragma unroll
        for (int half = 0; half < 2; ++half) {
            const int c = t + half * 256;
            if (c < NC) {
                const float4* wr = (const float4*)(Wc + (size_t)c * EMB);
                float d = bc[c];
#pragma unroll 8
                for (int k = 0; k < EMB / 4; ++k) {
                    float4 w4 = wr[k];
                    float4 fv = f4[k];
                    d += w4.x * fv.x + w4.y * fv.y
                       + w4.z * fv.z + w4.w * fv.w;
                }
                s_log[c] = d;
                lmax = fmaxf(lmax, d);
            }
        }

        // block max: wave shuffle + 4-slot LDS
#pragma unroll
        for (int o = 32; o > 0; o >>= 1)
            lmax = fmaxf(lmax, __shfl_xor(lmax, o));
        if (lane == 0) s_max4[wave] = lmax;
        __syncthreads();
        const float mv = fmaxf(fmaxf(s_max4[0], s_max4[1]),
                               fmaxf(s_max4[2], s_max4[3]));

        float lsum = 0.0f;
#pragma unroll
        for (int half = 0; half < 2; ++half) {
            const int c = t + half * 256;
            if (c < NC) lsum += expf(s_log[c] - mv);
        }
#pragma unroll
        for (int o = 32; o > 0; o >>= 1)
            lsum += __shfl_xor(lsum, o);
        if (lane == 0) s_sum4[wave] = lsum;
        __syncthreads();

        if (t == 0) {
            const float tot = s_sum4[0] + s_sum4[1] + s_sum4[2] + s_sum4[3];
            int lab = (tf > (float)NC) ? (NC - 1) : ((int)tf - 1);
            lab = min(max(lab, 0), NC - 1);
            out5 = logf(tot) + mv - s_log[lab];

            const float* bsb = bs  + (size_t)b * 2 * HW;
            const float* ofb = off + (size_t)b * 2 * HW;
            out0 = fabsf(bsb[pix]      - bh * 608.0f)
                 + fabsf(bsb[HW + pix] - bw * 1088.0f);
            out1 = fabsf(ofb[pix]      - (rf - fr))
                 + fabsf(ofb[HW + pix] - (cf - fc));
        }
    }

    // plain store of this block's full row (8 floats, block-private line)
    if (t == 0) {
        float* row = partials + (size_t)gb * 8;
        row[0] = out0; row[1] = out1; row[2] = out2; row[3] = out3;
        row[4] = out4; row[5] = out5; row[6] = 0.0f; row[7] = 0.0f;
    }
}

// ---------------------------------------------------------------------------
// Final reduce: 1 block, stream-ordered after main_kernel (dispatch boundary
// provides cross-XCD visibility). Sums 768 rows, writes the 6 outputs.
// ---------------------------------------------------------------------------
__global__ void final_kernel(const float* __restrict__ partials,
                             float* __restrict__ out) {
    __shared__ float s_fin[4][6];
    const int t = threadIdx.x;
    const int wave = t >> 6;
    const int lane = t & 63;

    float v[6] = {0, 0, 0, 0, 0, 0};
    for (int r = t; r < TOTAL_BLOCKS; r += 256) {
        const float* row = partials + (size_t)r * 8;
#pragma unroll
        for (int j = 0; j < 6; ++j) v[j] += row[j];
    }
#pragma unroll
    for (int o = 32; o > 0; o >>= 1)
#pragma unroll
        for (int j = 0; j < 6; ++j) v[j] += __shfl_xor(v[j], o);
    if (lane == 0)
#pragma unroll
        for (int j = 0; j < 6; ++j) s_fin[wave][j] = v[j];
    __syncthreads();

    if (t == 0) {
        float a[6];
#pragma unroll
        for (int j = 0; j < 6; ++j)
            a[j] = s_fin[0][j] + s_fin[1][j] + s_fin[2][j] + s_fin[3][j];
        const float bsl = a[0], ofl = a[1], pl = a[2],
                    nl = a[3], np = a[4], re = a[5];
        const float hmv   = (np >= 1.0f) ? (-(pl + nl) / np) : (-nl);
        const float reidl = re / (float)Nn;
        const float det   = hmv + 0.1f * bsl + ofl;
        out[0] = bsl;
        out[1] = ofl;
        out[2] = det;
        out[3] = hmv;
        out[4] = reidl;
        out[5] = det + reidl;
    }
}

extern "C" void kernel_launch(void* const* d_in, const int* in_sizes, int n_in,
                              void* d_out, int out_size, void* d_ws, size_t ws_size,
                              hipStream_t stream) {
    const float* hm   = (const float*)d_in[0];  // (B,1,H,W)
    const float* bs   = (const float*)d_in[1];  // (B,2,H,W)
    const float* off  = (const float*)d_in[2];  // (B,2,H,W)
    const float* reid = (const float*)d_in[3];  // (B,128,H,W)
    const float* gt   = (const float*)d_in[4];  // (B,N,5)
    const float* Wc   = (const float*)d_in[5];  // (500,128)
    const float* bc   = (const float*)d_in[6];  // (500,)
    float* out = (float*)d_out;
    float* partials = (float*)d_ws;             // [768][8] floats

    hipLaunchKernelGGL(main_kernel, dim3(TOTAL_BLOCKS), dim3(256), 0, stream,
                       hm, bs, off, reid, gt, Wc, bc, partials);
    hipLaunchKernelGGL(final_kernel, dim3(1), dim3(256), 0, stream,
                       partials, out);
}